// Round 3
// baseline (171.069 us; speedup 1.0000x reference)
//
#include <hip/hip_runtime.h>
#include <hip/hip_bf16.h>

typedef __attribute__((ext_vector_type(8))) short bf16x8;
typedef __attribute__((ext_vector_type(4))) float f32x4;

#define B_ 2048
#define S_ 200
#define D_ 128
#define H_ 64
#define SP 208   /* S padded to 13*16 */
#define NT 13    /* 16-row M-tiles per batch */

// ws layout (total ~2.16 MB)
#define WS_WT 0                        // bf16 W'^T [64 n][256 k]   = 32768 B
#define WS_TA 32768                    // f32 tA [2048][64]         = 524288 B
#define WS_LG (32768 + 524288)         // f32 logits [2048][208]    = 1703936 B

static __device__ __forceinline__ unsigned short f2bf(float f) {
    union { float f; unsigned u; } v; v.f = f;
    unsigned r = v.u + 0x7fffu + ((v.u >> 16) & 1u);   // RNE
    return (unsigned short)(r >> 16);
}

// LDS X layout: 32 k-groups (g: 0..15 = h, 16..31 = t*h) x 16 rows x 16B.
// XOR swizzle keeps both ds_write and MFMA ds_read_b128 conflict-light
// (measured 0 SQ_LDS_BANK_CONFLICT with this scheme in R1).
__device__ __forceinline__ int xoff(int g, int r) {
    return (((g << 4) + r) << 4) ^ ((g & 7) << 4);
}

// ---- kernel A: fold W' to bf16, compute exact fp32 tA[b][n] ----
__global__ __launch_bounds__(256)
void prep_kernel(const float* __restrict__ tgt, const float* __restrict__ W1,
                 const float* __restrict__ b1, char* __restrict__ ws)
{
    __shared__ float tl[16][128];
    const int tid = threadIdx.x;
    const int b0 = blockIdx.x * 16;
    for (int i = tid; i < 512; i += 256) {
        int bb = i >> 5, q = i & 31;
        *(float4*)&tl[bb][q * 4] = *(const float4*)(tgt + (size_t)(b0 + bb) * D_ + q * 4);
    }
    __syncthreads();
    const int n = tid & 63;
    const int bb0 = (tid >> 6) * 4;
    float a0 = 0.f, a1 = 0.f, a2 = 0.f, a3 = 0.f;
    for (int d = 0; d < 128; ++d) {
        float wsum = W1[d * H_ + n] + W1[(256 + d) * H_ + n];  // W1a + W1c
        a0 = fmaf(tl[bb0 + 0][d], wsum, a0);
        a1 = fmaf(tl[bb0 + 1][d], wsum, a1);
        a2 = fmaf(tl[bb0 + 2][d], wsum, a2);
        a3 = fmaf(tl[bb0 + 3][d], wsum, a3);
    }
    const float bn = b1[n];
    float* tA = (float*)(ws + WS_TA);
    tA[(size_t)(b0 + bb0 + 0) * H_ + n] = a0 + bn;
    tA[(size_t)(b0 + bb0 + 1) * H_ + n] = a1 + bn;
    tA[(size_t)(b0 + bb0 + 2) * H_ + n] = a2 + bn;
    tA[(size_t)(b0 + bb0 + 3) * H_ + n] = a3 + bn;

    if (blockIdx.x == 0) {
        // W'[k][n] = (k<128) ? W1b-W1c : W1d ; stored transposed [n][k] bf16
        unsigned short* wt = (unsigned short*)(ws + WS_WT);
        for (int i = tid; i < 16384; i += 256) {
            int nn = i >> 8, k = i & 255;
            float f = (k < 128) ? W1[(128 + k) * H_ + nn] - W1[(256 + k) * H_ + nn]
                                : W1[(256 + k) * H_ + nn];
            wt[nn * 256 + k] = f2bf(f);
        }
    }
}

// ---- kernel B: one 16-row M-tile per block; logits to ws ----
__global__ __launch_bounds__(256)
void logits_kernel(const float* __restrict__ tgt, const float* __restrict__ hist,
                   const float* __restrict__ W2, char* __restrict__ ws)
{
    __shared__ __align__(16) char Xb[8192];
    __shared__ float tl[128];
    __shared__ float partial[4][16];
    const int tid  = threadIdx.x;
    const int b    = blockIdx.x;
    const int s0   = blockIdx.y << 4;
    const int lane = tid & 63;
    const int wv   = tid >> 6;
    const int n    = (wv << 4) + (lane & 15);
    const int kq   = (lane >> 4) << 3;

    if (tid < 32) {
        float4 tv = ((const float4*)(tgt + (size_t)b * D_))[tid];
        *(float4*)&tl[tid * 4] = tv;
    }
    // B fragments: one 16B load each from folded W'^T (L2-hot)
    const unsigned short* wt = (const unsigned short*)(ws + WS_WT);
    bf16x8 bfrag[8];
    #pragma unroll
    for (int ks = 0; ks < 8; ++ks)
        bfrag[ks] = *(const bf16x8*)(wt + n * 256 + ks * 32 + kq);
    const float ta  = ((const float*)(ws + WS_TA))[(size_t)b * H_ + n];
    const float w2n = W2[n];
    __syncthreads();

    // stage 16 rows: X = [h | t*h] as bf16
    for (int i = tid; i < 512; i += 256) {
        int r = i >> 5, q = i & 31;
        int s = s0 + r;
        float4 hv = make_float4(0.f, 0.f, 0.f, 0.f);
        if (s < S_) hv = *(const float4*)(hist + ((size_t)b * S_ + s) * D_ + q * 4);
        float4 tv = *(const float4*)&tl[q * 4];
        ushort4 hh, th;
        hh.x = f2bf(hv.x);        hh.y = f2bf(hv.y);
        hh.z = f2bf(hv.z);        hh.w = f2bf(hv.w);
        th.x = f2bf(hv.x * tv.x); th.y = f2bf(hv.y * tv.y);
        th.z = f2bf(hv.z * tv.z); th.w = f2bf(hv.w * tv.w);
        int g = q >> 1, sub = (q & 1) << 3;
        *(ushort4*)(Xb + xoff(g,      r) + sub) = hh;
        *(ushort4*)(Xb + xoff(g + 16, r) + sub) = th;
    }
    __syncthreads();

    f32x4 acc = {0.f, 0.f, 0.f, 0.f};
    const int r = lane & 15;
    #pragma unroll
    for (int ks = 0; ks < 8; ++ks) {
        int gg = (ks << 2) + (lane >> 4);
        bf16x8 a = *(const bf16x8*)(Xb + xoff(gg, r));
        acc = __builtin_amdgcn_mfma_f32_16x16x32_bf16(a, bfrag[ks], acc, 0, 0, 0);
    }
    // D layout: col = lane&15 (n), row = (lane>>4)*4 + e; reduce over n
    #pragma unroll
    for (int e = 0; e < 4; ++e) {
        float vv = fmaxf(acc[e] + ta, 0.f) * w2n;
        vv += __shfl_xor(vv, 1);
        vv += __shfl_xor(vv, 2);
        vv += __shfl_xor(vv, 4);
        vv += __shfl_xor(vv, 8);
        if ((lane & 15) == 0)
            partial[wv][((lane >> 4) << 2) + e] = vv;
    }
    __syncthreads();
    if (tid < 16) {
        float lg = partial[0][tid] + partial[1][tid] + partial[2][tid] + partial[3][tid];
        ((float*)(ws + WS_LG))[(size_t)b * SP + s0 + tid] = lg;
    }
}

// ---- kernel C: softmax + fp32 weighted sum (history L3-served) ----
__global__ __launch_bounds__(256)
void out_kernel(const float* __restrict__ hist, const int* __restrict__ mask,
                const float* __restrict__ b2, const char* __restrict__ ws,
                float* __restrict__ out)
{
    __shared__ float wl[SP];
    __shared__ float red[8];
    __shared__ float psum[8][128];
    const int tid  = threadIdx.x;
    const int b    = blockIdx.x;
    const int lane = tid & 63;
    const int wv   = tid >> 6;

    float lg = -1e30f;
    if (tid < SP) {
        float v = ((const float*)(ws + WS_LG))[(size_t)b * SP + tid];
        int m = (tid < S_) ? mask[(size_t)b * S_ + tid] : 0;
        lg = m ? (v + b2[0]) : -1e9f;
    }
    float v = lg;
    #pragma unroll
    for (int m = 1; m < 64; m <<= 1) v = fmaxf(v, __shfl_xor(v, m));
    if (lane == 0) red[wv] = v;
    __syncthreads();
    const float mx = fmaxf(fmaxf(red[0], red[1]), fmaxf(red[2], red[3]));
    float p = (tid < SP) ? expf(lg - mx) : 0.f;
    float sv = p;
    #pragma unroll
    for (int m = 1; m < 64; m <<= 1) sv += __shfl_xor(sv, m);
    if (lane == 0) red[4 + wv] = sv;
    __syncthreads();
    const float denom = red[4] + red[5] + red[6] + red[7];
    if (tid < SP) wl[tid] = p / denom;
    __syncthreads();

    // out[b][d] = sum_s w[s]*hist[b][s][d]; 8 s-stripes x 32 d-quads
    const int dq     = tid & 31;
    const int stripe = tid >> 5;
    const int sbeg   = stripe * 26;
    f32x4 acc = {0.f, 0.f, 0.f, 0.f};
    const float* hp = hist + ((size_t)b * S_ + sbeg) * D_ + dq * 4;
    #pragma unroll 2
    for (int i = 0; i < 26; ++i) {
        int s = sbeg + i;
        if (s < S_) {
            float4 hv = *(const float4*)(hp + (size_t)i * D_);
            float w = wl[s];
            acc[0] = fmaf(w, hv.x, acc[0]);
            acc[1] = fmaf(w, hv.y, acc[1]);
            acc[2] = fmaf(w, hv.z, acc[2]);
            acc[3] = fmaf(w, hv.w, acc[3]);
        }
    }
    *(f32x4*)&psum[stripe][dq * 4] = acc;
    __syncthreads();
    if (tid < 128) {
        float o = 0.f;
        #pragma unroll
        for (int st = 0; st < 8; ++st) o += psum[st][tid];
        out[(size_t)b * D_ + tid] = o;
    }
}

extern "C" void kernel_launch(void* const* d_in, const int* in_sizes, int n_in,
                              void* d_out, int out_size, void* d_ws, size_t ws_size,
                              hipStream_t stream) {
    const float* tgt  = (const float*)d_in[0];
    const float* hist = (const float*)d_in[1];
    const int*   mask = (const int*)d_in[2];
    const float* W1   = (const float*)d_in[3];
    const float* b1   = (const float*)d_in[4];
    const float* W2   = (const float*)d_in[5];
    const float* b2   = (const float*)d_in[6];
    float* out = (float*)d_out;
    char* ws = (char*)d_ws;

    prep_kernel<<<128, 256, 0, stream>>>(tgt, W1, b1, ws);
    logits_kernel<<<dim3(B_, NT), 256, 0, stream>>>(tgt, hist, W2, ws);
    out_kernel<<<B_, 256, 0, stream>>>(hist, mask, b2, ws, out);
}

// Round 4
// 81.865 us; speedup vs baseline: 2.0896x; 2.0896x over previous
//
#include <hip/hip_runtime.h>
#include <hip/hip_bf16.h>

typedef __attribute__((ext_vector_type(8))) short bf16x8;
typedef __attribute__((ext_vector_type(4))) float f32x4;

#define B_ 2048
#define S_ 200
#define D_ 128
#define H_ 64
#define NT 13
#define LOG2E 1.44269504f

// ws layout
#define WS_TA 0                       // f32 tA[2048][64]   = 512 KB
#define WS_BC (512*1024)              // f32 bcT[64][128]   = 32 KB  (W1b - W1c, transposed)
#define WS_DT (512*1024 + 32768)      // f32 dT [64][128]   = 32 KB  (W1d, transposed)

static __device__ __forceinline__ unsigned short f2bf(float f) {
    union { float f; unsigned u; } v; v.f = f;
    unsigned r = v.u + 0x7fffu + ((v.u >> 16) & 1u);   // RNE
    return (unsigned short)(r >> 16);
}

// ---- prep: exact fp32 tA[b][n] = t.(W1a+W1c)+b1 ; transpose folded weights ----
__global__ __launch_bounds__(256)
void prep_kernel(const float* __restrict__ tgt, const float* __restrict__ W1,
                 const float* __restrict__ b1, char* __restrict__ ws)
{
    __shared__ float tl[16][128];
    const int tid = threadIdx.x;
    const int b0 = blockIdx.x * 16;
    for (int i = tid; i < 512; i += 256) {
        int bb = i >> 5, q = i & 31;
        *(float4*)&tl[bb][q * 4] = *(const float4*)(tgt + (size_t)(b0 + bb) * D_ + q * 4);
    }
    __syncthreads();
    const int n = tid & 63;
    const int bb0 = (tid >> 6) * 4;
    float a0 = 0.f, a1 = 0.f, a2 = 0.f, a3 = 0.f;
    for (int d = 0; d < 128; ++d) {
        float wsum = W1[d * H_ + n] + W1[(256 + d) * H_ + n];  // W1a + W1c
        a0 = fmaf(tl[bb0 + 0][d], wsum, a0);
        a1 = fmaf(tl[bb0 + 1][d], wsum, a1);
        a2 = fmaf(tl[bb0 + 2][d], wsum, a2);
        a3 = fmaf(tl[bb0 + 3][d], wsum, a3);
    }
    const float bn = b1[n];
    float* tA = (float*)(ws + WS_TA);
    tA[(size_t)(b0 + bb0 + 0) * H_ + n] = a0 + bn;
    tA[(size_t)(b0 + bb0 + 1) * H_ + n] = a1 + bn;
    tA[(size_t)(b0 + bb0 + 2) * H_ + n] = a2 + bn;
    tA[(size_t)(b0 + bb0 + 3) * H_ + n] = a3 + bn;

    if (blockIdx.x == 0) {
        float* bcT = (float*)(ws + WS_BC);
        float* dT  = (float*)(ws + WS_DT);
        for (int i = tid; i < 8192; i += 256) {
            int nn = i >> 7, k = i & 127;
            bcT[nn * 128 + k] = W1[(128 + k) * H_ + nn] - W1[(256 + k) * H_ + nn];
            dT [nn * 128 + k] = W1[(384 + k) * H_ + nn];
        }
    }
}

// ---- fused: per-batch block; MFMA logits + online softmax + fp32 PV, one pass ----
__global__ __launch_bounds__(256)
void din_fused(const float* __restrict__ tgt, const float* __restrict__ hist,
               const int* __restrict__ mask, const float* __restrict__ W2,
               const char* __restrict__ ws, float* __restrict__ out)
{
    __shared__ __align__(16) char wt[16384];   // swizzled bf16 W''^T [n=64][k=128]
    __shared__ float t_lds[128];
    __shared__ float sm[4][16];
    __shared__ float omg[4][128];
    __shared__ float lm[4][2];

    const int tid  = threadIdx.x;
    const int b    = blockIdx.x;
    const int lane = tid & 63;
    const int wv   = tid >> 6;
    const int lo   = lane & 15;
    const int hi   = lane >> 4;

    if (tid < 32) {
        float4 tv = ((const float4*)(tgt + (size_t)b * D_))[tid];
        *(float4*)&t_lds[tid * 4] = tv;
    }
    __syncthreads();

    // phase 0: W''[k][n] = (W1b-W1c)[k][n] + t[k]*W1d[k][n], bf16, stored [n][k] swizzled
    {
        const float* bcT = (const float*)(ws + WS_BC);
        const float* dT  = (const float*)(ws + WS_DT);
        #pragma unroll
        for (int j = 0; j < 4; ++j) {
            int idx = tid + j * 256;           // 1024 chunks of 8 k's
            int n = idx >> 4, kb = idx & 15;
            const float* bc = bcT + n * 128 + kb * 8;
            const float* dd = dT  + n * 128 + kb * 8;
            const float* tt = t_lds + kb * 8;
            bf16x8 v;
            #pragma unroll
            for (int e = 0; e < 8; ++e)
                v[e] = (short)f2bf(fmaf(tt[e], dd[e], bc[e]));
            int byteoff = (n * 256 + kb * 16) ^ ((n & 7) << 4);
            *(bf16x8*)(wt + byteoff) = v;
        }
    }
    __syncthreads();

    // B fragments in registers: bf[ks][ng], n = ng*16+lo, k = ks*32 + hi*8 + e
    bf16x8 bf[4][4];
    #pragma unroll
    for (int ng = 0; ng < 4; ++ng) {
        int n = ng * 16 + lo;
        #pragma unroll
        for (int ks = 0; ks < 4; ++ks) {
            int byteoff = (n * 256 + ks * 64 + hi * 16) ^ ((n & 7) << 4);
            bf[ks][ng] = *(const bf16x8*)(wt + byteoff);
        }
    }
    float ta[4], w2[4];
    #pragma unroll
    for (int ng = 0; ng < 4; ++ng) {
        int n = ng * 16 + lo;
        ta[ng] = ((const float*)(ws + WS_TA))[(size_t)b * H_ + n];
        w2[ng] = W2[n] * LOG2E;               // base-2 logit domain
    }

    // online state (per wave; lo-reduce deferred to end)
    float o[4][8];
    #pragma unroll
    for (int ks = 0; ks < 4; ++ks)
        #pragma unroll
        for (int e = 0; e < 8; ++e) o[ks][e] = 0.f;
    float l = 0.f, m2 = -1e30f;

    for (int t = wv; t < NT; t += 4) {
        const int s0 = t << 4;
        int srow = s0 + lo; if (srow > S_ - 1) srow = S_ - 1;
        const float* hp = hist + ((size_t)b * S_ + srow) * D_;
        f32x4 st[4][2];
        #pragma unroll
        for (int ks = 0; ks < 4; ++ks) {
            st[ks][0] = *(const f32x4*)(hp + ks * 32 + hi * 8);
            st[ks][1] = *(const f32x4*)(hp + ks * 32 + hi * 8 + 4);
        }
        // fp32 -> bf16 A fragments
        f32x4 acc[4];
        #pragma unroll
        for (int ng = 0; ng < 4; ++ng) acc[ng] = (f32x4){0.f, 0.f, 0.f, 0.f};
        #pragma unroll
        for (int ks = 0; ks < 4; ++ks) {
            bf16x8 a;
            #pragma unroll
            for (int e = 0; e < 4; ++e) {
                a[e]     = (short)f2bf(st[ks][0][e]);
                a[e + 4] = (short)f2bf(st[ks][1][e]);
            }
            #pragma unroll
            for (int ng = 0; ng < 4; ++ng)
                acc[ng] = __builtin_amdgcn_mfma_f32_16x16x32_bf16(a, bf[ks][ng], acc[ng], 0, 0, 0);
        }
        // logits (base-2): rows r = hi*4+e ; reduce over n (regs + 16-lane shfl)
        float vv[4];
        #pragma unroll
        for (int e = 0; e < 4; ++e) {
            float s = fmaxf(acc[0][e] + ta[0], 0.f) * w2[0];
            s = fmaf(fmaxf(acc[1][e] + ta[1], 0.f), w2[1], s);
            s = fmaf(fmaxf(acc[2][e] + ta[2], 0.f), w2[2], s);
            s = fmaf(fmaxf(acc[3][e] + ta[3], 0.f), w2[3], s);
            vv[e] = s;
        }
        #pragma unroll
        for (int e = 0; e < 4; ++e) {
            vv[e] += __shfl_xor(vv[e], 1);
            vv[e] += __shfl_xor(vv[e], 2);
            vv[e] += __shfl_xor(vv[e], 4);
            vv[e] += __shfl_xor(vv[e], 8);
        }
        // mask (int4 per hi-group of 4 rows; clamp keeps the load in-bounds)
        {
            int mrow = s0 + hi * 4;
            int mclamp = mrow > S_ - 4 ? S_ - 4 : mrow;
            int4 mv = *(const int4*)(mask + (size_t)b * S_ + mclamp);
            vv[0] = (mrow + 0 < S_ && mv.x) ? vv[0] : -1e30f;
            vv[1] = (mrow + 1 < S_ && mv.y) ? vv[1] : -1e30f;
            vv[2] = (mrow + 2 < S_ && mv.z) ? vv[2] : -1e30f;
            vv[3] = (mrow + 3 < S_ && mv.w) ? vv[3] : -1e30f;
        }
        float tmax = fmaxf(fmaxf(vv[0], vv[1]), fmaxf(vv[2], vv[3]));
        tmax = fmaxf(tmax, __shfl_xor(tmax, 16));
        tmax = fmaxf(tmax, __shfl_xor(tmax, 32));
        if (tmax > m2 + 11.5f) {               // defer-rescale (~8 nats in bits)
            float r = exp2f(m2 - tmax);        // first tile: exp2(-huge)=0, state stays 0
            #pragma unroll
            for (int ks = 0; ks < 4; ++ks)
                #pragma unroll
                for (int e = 0; e < 8; ++e) o[ks][e] *= r;
            l *= r;
            m2 = tmax;
        }
        // broadcast row logits to the lanes holding those staged rows (wave-local LDS)
        if (lo == 0)
            *(float4*)&sm[wv][hi * 4] = make_float4(vv[0], vv[1], vv[2], vv[3]);
        float lg2 = sm[wv][lo];
        float p = (lg2 > -1e29f) ? exp2f(lg2 - m2) : 0.f;
        l += p;
        #pragma unroll
        for (int ks = 0; ks < 4; ++ks) {
            o[ks][0] = fmaf(p, st[ks][0][0], o[ks][0]);
            o[ks][1] = fmaf(p, st[ks][0][1], o[ks][1]);
            o[ks][2] = fmaf(p, st[ks][0][2], o[ks][2]);
            o[ks][3] = fmaf(p, st[ks][0][3], o[ks][3]);
            o[ks][4] = fmaf(p, st[ks][1][0], o[ks][4]);
            o[ks][5] = fmaf(p, st[ks][1][1], o[ks][5]);
            o[ks][6] = fmaf(p, st[ks][1][2], o[ks][6]);
            o[ks][7] = fmaf(p, st[ks][1][3], o[ks][7]);
        }
    }

    // reduce over the 16 lo-lanes (deferred)
    #pragma unroll
    for (int ks = 0; ks < 4; ++ks)
        #pragma unroll
        for (int e = 0; e < 8; ++e) {
            float v = o[ks][e];
            v += __shfl_xor(v, 1);
            v += __shfl_xor(v, 2);
            v += __shfl_xor(v, 4);
            v += __shfl_xor(v, 8);
            o[ks][e] = v;
        }
    l += __shfl_xor(l, 1);
    l += __shfl_xor(l, 2);
    l += __shfl_xor(l, 4);
    l += __shfl_xor(l, 8);

    if (lo == 0) {
        #pragma unroll
        for (int ks = 0; ks < 4; ++ks) {
            *(f32x4*)&omg[wv][ks * 32 + hi * 8]     = (f32x4){o[ks][0], o[ks][1], o[ks][2], o[ks][3]};
            *(f32x4*)&omg[wv][ks * 32 + hi * 8 + 4] = (f32x4){o[ks][4], o[ks][5], o[ks][6], o[ks][7]};
        }
        if (hi == 0) { lm[wv][0] = m2; lm[wv][1] = l; }
    }
    __syncthreads();

    // 4-way flash merge + normalize; b2 cancels in softmax
    if (tid < 128) {
        float mstar = fmaxf(fmaxf(lm[0][0], lm[1][0]), fmaxf(lm[2][0], lm[3][0]));
        float num = 0.f, den = 0.f;
        #pragma unroll
        for (int w = 0; w < 4; ++w) {
            float f = exp2f(lm[w][0] - mstar);
            num = fmaf(omg[w][tid], f, num);
            den = fmaf(lm[w][1], f, den);
        }
        out[(size_t)b * D_ + tid] = num / den;
    }
}

extern "C" void kernel_launch(void* const* d_in, const int* in_sizes, int n_in,
                              void* d_out, int out_size, void* d_ws, size_t ws_size,
                              hipStream_t stream) {
    const float* tgt  = (const float*)d_in[0];
    const float* hist = (const float*)d_in[1];
    const int*   mask = (const int*)d_in[2];
    const float* W1   = (const float*)d_in[3];
    const float* b1   = (const float*)d_in[4];
    const float* W2   = (const float*)d_in[5];
    const float* b2   = (const float*)d_in[6];
    (void)b2;  // cancels in softmax
    float* out = (float*)d_out;
    char* ws = (char*)d_ws;

    prep_kernel<<<128, 256, 0, stream>>>(tgt, W1, b1, ws);
    din_fused<<<B_, 256, 0, stream>>>(tgt, hist, mask, W2, ws, out);
}

// Round 5
// 75.737 us; speedup vs baseline: 2.2587x; 1.0809x over previous
//
#include <hip/hip_runtime.h>
#include <hip/hip_bf16.h>

typedef __attribute__((ext_vector_type(8))) short bf16x8;
typedef __attribute__((ext_vector_type(4))) float f32x4;

#define B_ 2048
#define S_ 200
#define D_ 128
#define H_ 64
#define NT 13
#define LOG2E 1.44269504f

// ws layout
#define WS_TA 0                       // f32 tA[2048][64]   = 512 KB
#define WS_BC (512*1024)              // f32 bcT[64][128]   = 32 KB  (W1b - W1c, transposed)
#define WS_DT (512*1024 + 32768)      // f32 dT [64][128]   = 32 KB  (W1d, transposed)

static __device__ __forceinline__ unsigned short f2bf(float f) {
    union { float f; unsigned u; } v; v.f = f;
    unsigned r = v.u + 0x7fffu + ((v.u >> 16) & 1u);   // RNE (prep path)
    return (unsigned short)(r >> 16);
}
static __device__ __forceinline__ short f2bf_hw(float f) {
    return (short)__builtin_bit_cast(unsigned short, __float2bfloat16(f));  // RNE, v_cvt_pk
}

// ---- prep: exact fp32 tA[b][n] = t.(W1a+W1c)+b1 ; transpose folded weights ----
__global__ __launch_bounds__(256)
void prep_kernel(const float* __restrict__ tgt, const float* __restrict__ W1,
                 const float* __restrict__ b1, char* __restrict__ ws)
{
    __shared__ float tl[16][128];
    const int tid = threadIdx.x;
    const int b0 = blockIdx.x * 16;
    for (int i = tid; i < 512; i += 256) {
        int bb = i >> 5, q = i & 31;
        *(float4*)&tl[bb][q * 4] = *(const float4*)(tgt + (size_t)(b0 + bb) * D_ + q * 4);
    }
    __syncthreads();
    const int n = tid & 63;
    const int bb0 = (tid >> 6) * 4;
    float a0 = 0.f, a1 = 0.f, a2 = 0.f, a3 = 0.f;
    for (int d = 0; d < 128; ++d) {
        float wsum = W1[d * H_ + n] + W1[(256 + d) * H_ + n];  // W1a + W1c
        a0 = fmaf(tl[bb0 + 0][d], wsum, a0);
        a1 = fmaf(tl[bb0 + 1][d], wsum, a1);
        a2 = fmaf(tl[bb0 + 2][d], wsum, a2);
        a3 = fmaf(tl[bb0 + 3][d], wsum, a3);
    }
    const float bn = b1[n];
    float* tA = (float*)(ws + WS_TA);
    tA[(size_t)(b0 + bb0 + 0) * H_ + n] = a0 + bn;
    tA[(size_t)(b0 + bb0 + 1) * H_ + n] = a1 + bn;
    tA[(size_t)(b0 + bb0 + 2) * H_ + n] = a2 + bn;
    tA[(size_t)(b0 + bb0 + 3) * H_ + n] = a3 + bn;

    if (blockIdx.x == 0) {
        float* bcT = (float*)(ws + WS_BC);
        float* dT  = (float*)(ws + WS_DT);
        for (int i = tid; i < 8192; i += 256) {
            int nn = i >> 7, k = i & 127;
            bcT[nn * 128 + k] = W1[(128 + k) * H_ + nn] - W1[(256 + k) * H_ + nn];
            dT [nn * 128 + k] = W1[(384 + k) * H_ + nn];
        }
    }
}

// ---- fused: per-batch block; prefetched MFMA logits + online softmax + fp32 PV ----
__global__ __launch_bounds__(256)
void din_fused(const float* __restrict__ tgt, const float* __restrict__ hist,
               const int* __restrict__ mask, const float* __restrict__ W2,
               const char* __restrict__ ws, float* __restrict__ out)
{
    __shared__ __align__(16) char wt[16384];   // swizzled bf16 W''^T [n=64][k=128]
    __shared__ float t_lds[128];
    __shared__ float sm[4][16];
    __shared__ float omg[4][128];
    __shared__ float lm[4][2];

    const int tid  = threadIdx.x;
    const int b    = blockIdx.x;
    const int lane = tid & 63;
    const int wv   = tid >> 6;
    const int lo   = lane & 15;
    const int hi   = lane >> 4;

    if (tid < 32) {
        float4 tv = ((const float4*)(tgt + (size_t)b * D_))[tid];
        *(float4*)&t_lds[tid * 4] = tv;
    }
    __syncthreads();

    // W''[k][n] = (W1b-W1c)[k][n] + t[k]*W1d[k][n], bf16, stored [n][k] XOR-swizzled
    {
        const float* bcT = (const float*)(ws + WS_BC);
        const float* dT  = (const float*)(ws + WS_DT);
        #pragma unroll
        for (int j = 0; j < 4; ++j) {
            int idx = tid + j * 256;
            int n = idx >> 4, kb = idx & 15;
            f32x4 bc0 = *(const f32x4*)(bcT + n * 128 + kb * 8);
            f32x4 bc1 = *(const f32x4*)(bcT + n * 128 + kb * 8 + 4);
            f32x4 dd0 = *(const f32x4*)(dT  + n * 128 + kb * 8);
            f32x4 dd1 = *(const f32x4*)(dT  + n * 128 + kb * 8 + 4);
            f32x4 t0  = *(const f32x4*)(t_lds + kb * 8);
            f32x4 t1  = *(const f32x4*)(t_lds + kb * 8 + 4);
            bf16x8 v;
            #pragma unroll
            for (int e = 0; e < 4; ++e) {
                v[e]     = f2bf_hw(fmaf(t0[e], dd0[e], bc0[e]));
                v[e + 4] = f2bf_hw(fmaf(t1[e], dd1[e], bc1[e]));
            }
            int byteoff = (n * 256 + kb * 16) ^ ((n & 7) << 4);
            *(bf16x8*)(wt + byteoff) = v;
        }
    }

    float ta[4], w2[4];
    #pragma unroll
    for (int ng = 0; ng < 4; ++ng) {
        int n = ng * 16 + lo;
        ta[ng] = ((const float*)(ws + WS_TA))[(size_t)b * H_ + n];
        w2[ng] = W2[n] * LOG2E;               // base-2 logit domain
    }
    __syncthreads();                           // W'' visible to all waves

    // loop-invariant swizzled LDS read offsets: addr = vbase[ng] + koff[ks]
    int vbase[4], koff[4];
    #pragma unroll
    for (int ng = 0; ng < 4; ++ng) vbase[ng] = (ng * 16 + lo) * 256;
    #pragma unroll
    for (int ks = 0; ks < 4; ++ks) koff[ks] = (ks * 64 + hi * 16) ^ ((lo & 7) << 4);

    float o[4][8];
    #pragma unroll
    for (int ks = 0; ks < 4; ++ks)
        #pragma unroll
        for (int e = 0; e < 8; ++e) o[ks][e] = 0.f;
    float l = 0.f, m2 = -1e30f;

    auto loadt = [&](f32x4 (&st)[4][2], int t) {
        int srow = (t << 4) + lo; if (srow > S_ - 1) srow = S_ - 1;
        const float* hp = hist + ((size_t)b * S_ + srow) * D_ + hi * 8;
        #pragma unroll
        for (int ks = 0; ks < 4; ++ks) {
            st[ks][0] = *(const f32x4*)(hp + ks * 32);
            st[ks][1] = *(const f32x4*)(hp + ks * 32 + 4);
        }
    };

    auto compt = [&](f32x4 (&st)[4][2], int t) {
        // fp32 -> bf16 A fragments (hw cvt_pk)
        bf16x8 af[4];
        #pragma unroll
        for (int ks = 0; ks < 4; ++ks)
            #pragma unroll
            for (int e = 0; e < 4; ++e) {
                af[ks][e]     = f2bf_hw(st[ks][0][e]);
                af[ks][e + 4] = f2bf_hw(st[ks][1][e]);
            }
        f32x4 acc[4];
        #pragma unroll
        for (int ng = 0; ng < 4; ++ng) acc[ng] = (f32x4){0.f, 0.f, 0.f, 0.f};
        #pragma unroll
        for (int ks = 0; ks < 4; ++ks)
            #pragma unroll
            for (int ng = 0; ng < 4; ++ng) {
                bf16x8 bfrag = *(const bf16x8*)(wt + vbase[ng] + koff[ks]);
                acc[ng] = __builtin_amdgcn_mfma_f32_16x16x32_bf16(af[ks], bfrag, acc[ng], 0, 0, 0);
            }
        // logits (base-2), rows r = hi*4+e; reduce over n
        float vv[4];
        #pragma unroll
        for (int e = 0; e < 4; ++e) {
            float s = fmaxf(acc[0][e] + ta[0], 0.f) * w2[0];
            s = fmaf(fmaxf(acc[1][e] + ta[1], 0.f), w2[1], s);
            s = fmaf(fmaxf(acc[2][e] + ta[2], 0.f), w2[2], s);
            s = fmaf(fmaxf(acc[3][e] + ta[3], 0.f), w2[3], s);
            vv[e] = s;
        }
        #pragma unroll
        for (int e = 0; e < 4; ++e) {
            vv[e] += __shfl_xor(vv[e], 1);
            vv[e] += __shfl_xor(vv[e], 2);
            vv[e] += __shfl_xor(vv[e], 4);
            vv[e] += __shfl_xor(vv[e], 8);
        }
        {
            int mrow = (t << 4) + hi * 4;
            int mclamp = mrow > S_ - 4 ? S_ - 4 : mrow;
            int4 mv = *(const int4*)(mask + (size_t)b * S_ + mclamp);
            vv[0] = (mrow + 0 < S_ && mv.x) ? vv[0] : -1e30f;
            vv[1] = (mrow + 1 < S_ && mv.y) ? vv[1] : -1e30f;
            vv[2] = (mrow + 2 < S_ && mv.z) ? vv[2] : -1e30f;
            vv[3] = (mrow + 3 < S_ && mv.w) ? vv[3] : -1e30f;
        }
        float tmax = fmaxf(fmaxf(vv[0], vv[1]), fmaxf(vv[2], vv[3]));
        tmax = fmaxf(tmax, __shfl_xor(tmax, 16));
        tmax = fmaxf(tmax, __shfl_xor(tmax, 32));
        if (tmax > m2 + 11.5f) {               // defer-rescale (T13)
            float r = exp2f(m2 - tmax);
            #pragma unroll
            for (int ks = 0; ks < 4; ++ks)
                #pragma unroll
                for (int e = 0; e < 8; ++e) o[ks][e] *= r;
            l *= r;
            m2 = tmax;
        }
        if (lo == 0)
            *(float4*)&sm[wv][hi * 4] = make_float4(vv[0], vv[1], vv[2], vv[3]);
        float lg2 = sm[wv][lo];
        float p = (lg2 > -1e29f) ? exp2f(lg2 - m2) : 0.f;
        l += p;
        #pragma unroll
        for (int ks = 0; ks < 4; ++ks) {
            o[ks][0] = fmaf(p, st[ks][0][0], o[ks][0]);
            o[ks][1] = fmaf(p, st[ks][0][1], o[ks][1]);
            o[ks][2] = fmaf(p, st[ks][0][2], o[ks][2]);
            o[ks][3] = fmaf(p, st[ks][0][3], o[ks][3]);
            o[ks][4] = fmaf(p, st[ks][1][0], o[ks][4]);
            o[ks][5] = fmaf(p, st[ks][1][1], o[ks][5]);
            o[ks][6] = fmaf(p, st[ks][1][2], o[ks][6]);
            o[ks][7] = fmaf(p, st[ks][1][3], o[ks][7]);
        }
    };

    // software-pipelined tile schedule (tiles wv, wv+4, wv+8 [, wv+12])
    f32x4 stA[4][2], stB[4][2];
    loadt(stA, wv);
    loadt(stB, wv + 4);
    compt(stA, wv);
    loadt(stA, wv + 8);
    compt(stB, wv + 4);
    if (wv + 12 < NT) {          // wave 0 only; wave-uniform branch
        loadt(stB, wv + 12);
        compt(stA, wv + 8);
        compt(stB, wv + 12);
    } else {
        compt(stA, wv + 8);
    }

    // deferred reduce over the 16 lo-lanes
    #pragma unroll
    for (int ks = 0; ks < 4; ++ks)
        #pragma unroll
        for (int e = 0; e < 8; ++e) {
            float v = o[ks][e];
            v += __shfl_xor(v, 1);
            v += __shfl_xor(v, 2);
            v += __shfl_xor(v, 4);
            v += __shfl_xor(v, 8);
            o[ks][e] = v;
        }
    l += __shfl_xor(l, 1);
    l += __shfl_xor(l, 2);
    l += __shfl_xor(l, 4);
    l += __shfl_xor(l, 8);

    if (lo == 0) {
        #pragma unroll
        for (int ks = 0; ks < 4; ++ks) {
            *(f32x4*)&omg[wv][ks * 32 + hi * 8]     = (f32x4){o[ks][0], o[ks][1], o[ks][2], o[ks][3]};
            *(f32x4*)&omg[wv][ks * 32 + hi * 8 + 4] = (f32x4){o[ks][4], o[ks][5], o[ks][6], o[ks][7]};
        }
        if (hi == 0) { lm[wv][0] = m2; lm[wv][1] = l; }
    }
    __syncthreads();

    // 4-way flash merge + normalize; b2 cancels in softmax
    if (tid < 128) {
        float mstar = fmaxf(fmaxf(lm[0][0], lm[1][0]), fmaxf(lm[2][0], lm[3][0]));
        float num = 0.f, den = 0.f;
        #pragma unroll
        for (int w = 0; w < 4; ++w) {
            float f = exp2f(lm[w][0] - mstar);
            num = fmaf(omg[w][tid], f, num);
            den = fmaf(lm[w][1], f, den);
        }
        out[(size_t)b * D_ + tid] = num / den;
    }
}

extern "C" void kernel_launch(void* const* d_in, const int* in_sizes, int n_in,
                              void* d_out, int out_size, void* d_ws, size_t ws_size,
                              hipStream_t stream) {
    const float* tgt  = (const float*)d_in[0];
    const float* hist = (const float*)d_in[1];
    const int*   mask = (const int*)d_in[2];
    const float* W1   = (const float*)d_in[3];
    const float* b1   = (const float*)d_in[4];
    const float* W2   = (const float*)d_in[5];
    const float* b2   = (const float*)d_in[6];
    (void)b2;  // cancels in softmax
    float* out = (float*)d_out;
    char* ws = (char*)d_ws;

    prep_kernel<<<128, 256, 0, stream>>>(tgt, W1, b1, ws);
    din_fused<<<B_, 256, 0, stream>>>(tgt, hist, mask, W2, ws, out);
}

// Round 6
// 71.954 us; speedup vs baseline: 2.3775x; 1.0526x over previous
//
#include <hip/hip_runtime.h>
#include <hip/hip_bf16.h>

typedef __attribute__((ext_vector_type(8))) short bf16x8;
typedef __attribute__((ext_vector_type(4))) float f32x4;

#define B_ 2048
#define S_ 200
#define D_ 128
#define H_ 64
#define NT 13
#define LOG2E 1.44269504f

// ws layout
#define WS_TA 0                       // f32 tA[2048][64]   = 512 KB
#define WS_BC (512*1024)              // f32 bcT[64][128]   = 32 KB  (W1b - W1c, transposed)
#define WS_DT (512*1024 + 32768)      // f32 dT [64][128]   = 32 KB  (W1d, transposed)

static __device__ __forceinline__ short f2bf_hw(float f) {
    return (short)__builtin_bit_cast(unsigned short, __float2bfloat16(f));  // RNE
}

// ---- prep: exact fp32 tA[b][n] = t.(W1a+W1c)+b1 ; transpose folded weights ----
__global__ __launch_bounds__(256)
void prep_kernel(const float* __restrict__ tgt, const float* __restrict__ W1,
                 const float* __restrict__ b1, char* __restrict__ ws)
{
    __shared__ float tl[16][128];
    const int tid = threadIdx.x;
    const int b0 = blockIdx.x * 16;
    for (int i = tid; i < 512; i += 256) {
        int bb = i >> 5, q = i & 31;
        *(float4*)&tl[bb][q * 4] = *(const float4*)(tgt + (size_t)(b0 + bb) * D_ + q * 4);
    }
    __syncthreads();
    const int n = tid & 63;
    const int bb0 = (tid >> 6) * 4;
    float a0 = 0.f, a1 = 0.f, a2 = 0.f, a3 = 0.f;
    for (int d = 0; d < 128; ++d) {
        float wsum = W1[d * H_ + n] + W1[(256 + d) * H_ + n];  // W1a + W1c
        a0 = fmaf(tl[bb0 + 0][d], wsum, a0);
        a1 = fmaf(tl[bb0 + 1][d], wsum, a1);
        a2 = fmaf(tl[bb0 + 2][d], wsum, a2);
        a3 = fmaf(tl[bb0 + 3][d], wsum, a3);
    }
    const float bn = b1[n];
    float* tA = (float*)(ws + WS_TA);
    tA[(size_t)(b0 + bb0 + 0) * H_ + n] = a0 + bn;
    tA[(size_t)(b0 + bb0 + 1) * H_ + n] = a1 + bn;
    tA[(size_t)(b0 + bb0 + 2) * H_ + n] = a2 + bn;
    tA[(size_t)(b0 + bb0 + 3) * H_ + n] = a3 + bn;

    if (blockIdx.x == 0) {
        float* bcT = (float*)(ws + WS_BC);
        float* dT  = (float*)(ws + WS_DT);
        for (int i = tid; i < 8192; i += 256) {
            int nn = i >> 7, k = i & 127;
            bcT[nn * 128 + k] = W1[(128 + k) * H_ + nn] - W1[(256 + k) * H_ + nn];
            dT [nn * 128 + k] = W1[(384 + k) * H_ + nn];
        }
    }
}

// ---- fused: swapped-operand MFMA => lane-local softmax; online flash; fp32 PV ----
__global__ __launch_bounds__(256, 2)
void din_fused(const float* __restrict__ tgt, const float* __restrict__ hist,
               const int* __restrict__ mask, const float* __restrict__ W2,
               const char* __restrict__ ws, float* __restrict__ out)
{
    __shared__ __align__(16) char wt[16384];   // swizzled bf16 W''^T [n=64][k=128]
    __shared__ float t_lds[128];
    __shared__ float omg[4][128];
    __shared__ float lm[4][2];

    const int tid  = threadIdx.x;
    const int b    = blockIdx.x;
    const int lane = tid & 63;
    const int wv   = tid >> 6;
    const int lo   = lane & 15;
    const int hi   = lane >> 4;

    if (tid < 32) {
        float4 tv = ((const float4*)(tgt + (size_t)b * D_))[tid];
        *(float4*)&t_lds[tid * 4] = tv;
    }
    __syncthreads();

    // W''[k][n] = (W1b-W1c)[k][n] + t[k]*W1d[k][n], bf16, stored [n][k] XOR-swizzled
    {
        const float* bcT = (const float*)(ws + WS_BC);
        const float* dT  = (const float*)(ws + WS_DT);
        #pragma unroll
        for (int j = 0; j < 4; ++j) {
            int idx = tid + j * 256;
            int n = idx >> 4, kb = idx & 15;
            f32x4 bc0 = *(const f32x4*)(bcT + n * 128 + kb * 8);
            f32x4 bc1 = *(const f32x4*)(bcT + n * 128 + kb * 8 + 4);
            f32x4 dd0 = *(const f32x4*)(dT  + n * 128 + kb * 8);
            f32x4 dd1 = *(const f32x4*)(dT  + n * 128 + kb * 8 + 4);
            f32x4 t0  = *(const f32x4*)(t_lds + kb * 8);
            f32x4 t1  = *(const f32x4*)(t_lds + kb * 8 + 4);
            bf16x8 v;
            #pragma unroll
            for (int e = 0; e < 4; ++e) {
                v[e]     = f2bf_hw(fmaf(t0[e], dd0[e], bc0[e]));
                v[e + 4] = f2bf_hw(fmaf(t1[e], dd1[e], bc1[e]));
            }
            int byteoff = (n * 256 + kb * 16) ^ ((n & 7) << 4);
            *(bf16x8*)(wt + byteoff) = v;
        }
    }

    // per-lane constants for n = ng*16 + hi*4 + e (swapped-D layout)
    f32x4 tav[4], w2v[4];
    #pragma unroll
    for (int ng = 0; ng < 4; ++ng) {
        tav[ng] = *(const f32x4*)((const float*)(ws + WS_TA) + (size_t)b * H_ + ng * 16 + hi * 4);
        f32x4 wv4 = *(const f32x4*)(W2 + ng * 16 + hi * 4);
        w2v[ng] = (f32x4){wv4[0] * LOG2E, wv4[1] * LOG2E, wv4[2] * LOG2E, wv4[3] * LOG2E};
    }
    __syncthreads();                           // W'' visible to all waves

    // A-operand (W'') swizzled LDS offsets: addr = vbase[ng] + koff[ks]
    int vbase[4], koff[4];
    #pragma unroll
    for (int ng = 0; ng < 4; ++ng) vbase[ng] = (ng * 16 + lo) * 256;
    #pragma unroll
    for (int ks = 0; ks < 4; ++ks) koff[ks] = (ks * 64 + hi * 16) ^ ((lo & 7) << 4);

    float o[4][8];
    #pragma unroll
    for (int ks = 0; ks < 4; ++ks)
        #pragma unroll
        for (int e = 0; e < 8; ++e) o[ks][e] = 0.f;
    float l = 0.f, m2 = -1e30f;

    auto loadt = [&](f32x4 (&st)[4][2], int t) {
        int srow = (t << 4) + lo; if (srow > S_ - 1) srow = S_ - 1;
        const float* hp = hist + ((size_t)b * S_ + srow) * D_ + hi * 8;
        #pragma unroll
        for (int ks = 0; ks < 4; ++ks) {
            st[ks][0] = *(const f32x4*)(hp + ks * 32);
            st[ks][1] = *(const f32x4*)(hp + ks * 32 + 4);
        }
    };

    auto compt = [&](f32x4 (&st)[4][2], int t) {
        // fp32 -> bf16 B fragments (history)
        bf16x8 bfr[4];
        #pragma unroll
        for (int ks = 0; ks < 4; ++ks)
            #pragma unroll
            for (int e = 0; e < 4; ++e) {
                bfr[ks][e]     = f2bf_hw(st[ks][0][e]);
                bfr[ks][e + 4] = f2bf_hw(st[ks][1][e]);
            }
        // swapped MFMA: D[n,s] ; A = W''^T frags (LDS), B = history frags
        f32x4 acc[4];
        #pragma unroll
        for (int ng = 0; ng < 4; ++ng) acc[ng] = (f32x4){0.f, 0.f, 0.f, 0.f};
        #pragma unroll
        for (int ks = 0; ks < 4; ++ks)
            #pragma unroll
            for (int ng = 0; ng < 4; ++ng) {
                bf16x8 afrag = *(const bf16x8*)(wt + vbase[ng] + koff[ks]);
                acc[ng] = __builtin_amdgcn_mfma_f32_16x16x32_bf16(afrag, bfr[ks], acc[ng], 0, 0, 0);
            }
        // lane-local relu-dot over 16 n-values (n = ng*16 + hi*4 + e), s = t*16+lo
        float sum = 0.f;
        #pragma unroll
        for (int ng = 0; ng < 4; ++ng)
            #pragma unroll
            for (int e = 0; e < 4; ++e)
                sum = fmaf(fmaxf(acc[ng][e] + tav[ng][e], 0.f), w2v[ng][e], sum);
        // n-sum across the 4 hi groups: 2 butterflies -> uniform across hi
        sum += __shfl_xor(sum, 16);
        sum += __shfl_xor(sum, 32);
        // mask for this lane's s-row
        int srow = (t << 4) + lo;
        int mc = srow < S_ ? srow : S_ - 1;
        int ok = (srow < S_) ? mask[(size_t)b * S_ + mc] : 0;
        float lg = ok ? sum : -1e30f;
        // tile max over the 16 lo-lanes: 4 butterflies -> wave-uniform
        float tm = lg;
        tm = fmaxf(tm, __shfl_xor(tm, 1));
        tm = fmaxf(tm, __shfl_xor(tm, 2));
        tm = fmaxf(tm, __shfl_xor(tm, 4));
        tm = fmaxf(tm, __shfl_xor(tm, 8));
        if (tm > m2 + 11.5f) {                 // defer-rescale (T13)
            float r = exp2f(m2 - tm);
            #pragma unroll
            for (int ks = 0; ks < 4; ++ks)
                #pragma unroll
                for (int e = 0; e < 8; ++e) o[ks][e] *= r;
            l *= r;
            m2 = tm;
        }
        float p = ok ? exp2f(lg - m2) : 0.f;
        l += p;
        #pragma unroll
        for (int ks = 0; ks < 4; ++ks) {
            o[ks][0] = fmaf(p, st[ks][0][0], o[ks][0]);
            o[ks][1] = fmaf(p, st[ks][0][1], o[ks][1]);
            o[ks][2] = fmaf(p, st[ks][0][2], o[ks][2]);
            o[ks][3] = fmaf(p, st[ks][0][3], o[ks][3]);
            o[ks][4] = fmaf(p, st[ks][1][0], o[ks][4]);
            o[ks][5] = fmaf(p, st[ks][1][1], o[ks][5]);
            o[ks][6] = fmaf(p, st[ks][1][2], o[ks][6]);
            o[ks][7] = fmaf(p, st[ks][1][3], o[ks][7]);
        }
    };

    // software-pipelined tile schedule (tiles wv, wv+4, wv+8 [, wv+12])
    f32x4 stA[4][2], stB[4][2];
    loadt(stA, wv);
    loadt(stB, wv + 4);
    compt(stA, wv);
    loadt(stA, wv + 8);
    compt(stB, wv + 4);
    if (wv + 12 < NT) {          // wave-uniform branch (wave 0 only)
        loadt(stB, wv + 12);
        compt(stA, wv + 8);
        compt(stB, wv + 12);
    } else {
        compt(stA, wv + 8);
    }

    // deferred reduce over the 16 lo-lanes
    #pragma unroll
    for (int ks = 0; ks < 4; ++ks)
        #pragma unroll
        for (int e = 0; e < 8; ++e) {
            float v = o[ks][e];
            v += __shfl_xor(v, 1);
            v += __shfl_xor(v, 2);
            v += __shfl_xor(v, 4);
            v += __shfl_xor(v, 8);
            o[ks][e] = v;
        }
    l += __shfl_xor(l, 1);
    l += __shfl_xor(l, 2);
    l += __shfl_xor(l, 4);
    l += __shfl_xor(l, 8);

    if (lo == 0) {
        #pragma unroll
        for (int ks = 0; ks < 4; ++ks) {
            *(f32x4*)&omg[wv][ks * 32 + hi * 8]     = (f32x4){o[ks][0], o[ks][1], o[ks][2], o[ks][3]};
            *(f32x4*)&omg[wv][ks * 32 + hi * 8 + 4] = (f32x4){o[ks][4], o[ks][5], o[ks][6], o[ks][7]};
        }
        if (hi == 0) { lm[wv][0] = m2; lm[wv][1] = l; }
    }
    __syncthreads();

    // 4-way flash merge + normalize; b2 cancels in softmax
    if (tid < 128) {
        float mstar = fmaxf(fmaxf(lm[0][0], lm[1][0]), fmaxf(lm[2][0], lm[3][0]));
        float num = 0.f, den = 0.f;
        #pragma unroll
        for (int w = 0; w < 4; ++w) {
            float f = exp2f(lm[w][0] - mstar);
            num = fmaf(omg[w][tid], f, num);
            den = fmaf(lm[w][1], f, den);
        }
        out[(size_t)b * D_ + tid] = num / den;
    }
}

extern "C" void kernel_launch(void* const* d_in, const int* in_sizes, int n_in,
                              void* d_out, int out_size, void* d_ws, size_t ws_size,
                              hipStream_t stream) {
    const float* tgt  = (const float*)d_in[0];
    const float* hist = (const float*)d_in[1];
    const int*   mask = (const int*)d_in[2];
    const float* W1   = (const float*)d_in[3];
    const float* b1   = (const float*)d_in[4];
    const float* W2   = (const float*)d_in[5];
    const float* b2   = (const float*)d_in[6];
    (void)b2;  // cancels in softmax
    float* out = (float*)d_out;
    char* ws = (char*)d_ws;

    prep_kernel<<<128, 256, 0, stream>>>(tgt, W1, b1, ws);
    din_fused<<<B_, 256, 0, stream>>>(tgt, hist, mask, W2, ws, out);
}